// Round 9
// baseline (299.115 us; speedup 1.0000x reference)
//
#include <hip/hip_runtime.h>
#include <hip/hip_bf16.h>
#include <math.h>

#define BB 4
#define VV 1024
#define HH 128
#define H2 64
#define EE 523776               // V*(V-1)/2
#define BE (BB * EE)            // 2095104
#define NTHR 256
#define NBLK 1024
#define NWAVE (NBLK * 4)        // 4096 waves
#define UNITS (BB * 1024 * 32)  // flat (b, i, jb2) units; 32 iters/wave exact

typedef __attribute__((ext_vector_type(8))) short bf16x8;
typedef __attribute__((ext_vector_type(4))) float f32x4;
typedef __attribute__((ext_vector_type(4))) unsigned u32x4;

#define KEEPV(x) asm volatile("" : "+v"(*(f32x4*)&(x)))
#define KEEPF(x) asm volatile("" : "+v"(x))

// RNE convert — staging only (outside hot loop).
__device__ __forceinline__ short f2bf(float f) {
    __hip_bfloat16 h = __float2bfloat16(f);
    return *reinterpret_cast<short*>(&h);
}

// ONE v_perm_b32: pack two f32 into bf16x2 by truncation (lo -> low half).
__device__ __forceinline__ unsigned pkbf(float lo, float hi) {
    return __builtin_amdgcn_perm(__float_as_uint(hi), __float_as_uint(lo),
                                 0x07060302u);
}

__device__ __forceinline__ bf16x8 relu_pack(f32x4 a, f32x4 b) {
    u32x4 r;
    r[0] = pkbf(fmaxf(a[0], 0.f), fmaxf(a[1], 0.f));
    r[1] = pkbf(fmaxf(a[2], 0.f), fmaxf(a[3], 0.f));
    r[2] = pkbf(fmaxf(b[0], 0.f), fmaxf(b[1], 0.f));
    r[3] = pkbf(fmaxf(b[2], 0.f), fmaxf(b[3], 0.f));
    return __builtin_bit_cast(bf16x8, r);
}

// ---------------------------------------------------------------------------
// Round 9: (a) vertex-block restructure — unit = (b, vertex i, 32-wide j
// block). Kills the sqrt decode AND the scattered gather: vi is one uniform
// load, vj is 32 consecutive rows (coalesced), prob stores are contiguous.
// Units fully below the diagonal skip immediately (~51%, ~20cyc each).
// (b) PROBE variant: same loop + full MFMA chain, synthetic features, no
// memory traffic, keep-alive (rule 17) — isolates the compute-pipeline floor
// that R3-R6's invariant ~54us VALU time could not explain.
// ---------------------------------------------------------------------------
template<int PROBE>
__global__ __launch_bounds__(NTHR, 2) void edge_blk(
    const float* __restrict__ vertices,  // [4,1024,3]
    const float* __restrict__ W1,        // [6,128]
    const float* __restrict__ b1,        // [128]
    const float* __restrict__ W2,        // [128,64]
    const float* __restrict__ b2,        // [64]
    const float* __restrict__ W3,        // [64]
    const float* __restrict__ b3,        // [1]
    float* __restrict__ out)             // [BE probs][2*EE indices-as-float]
{
    const int lane = threadIdx.x & 63;
    const int col  = lane & 15;          // j-offset within 16-edge group
    const int u    = lane >> 4;
    const int wid  = threadIdx.x >> 6;

    const f32x4 zero4 = {0.f, 0.f, 0.f, 0.f};

    // ---- persistent weight fragments (R6-identical layout) ----
    // L1: A1[p][q][r] = W1pad[k=8u+r][h], h = 32p + 8*(col>>2) + 4q + (col&3)
    bf16x8 A1[4][2];
#pragma unroll
    for (int p = 0; p < 4; ++p)
#pragma unroll
        for (int q = 0; q < 2; ++q) {
            const int h = 32 * p + 8 * (col >> 2) + 4 * q + (col & 3);
#pragma unroll
            for (int r = 0; r < 8; ++r) {
                const int k = 8 * u + r;
                float w = 0.0f;
                if (k < 6)       w = W1[k * HH + h];
                else if (k == 6) w = b1[h];
                A1[p][q][r] = f2bf(w);
            }
        }
    // L2: A2[mt][p][r] = W2[h=32p+8u+r][n2=16mt+col]
    bf16x8 A2[4][4];
#pragma unroll
    for (int mt = 0; mt < 4; ++mt)
#pragma unroll
        for (int p = 0; p < 4; ++p) {
            const int n2 = 16 * mt + col;
#pragma unroll
            for (int r = 0; r < 8; ++r) {
                const int h = 32 * p + 8 * u + r;
                A2[mt][p][r] = f2bf(W2[h * H2 + n2]);
            }
        }
    f32x4 cinit[4];
    float w3c[16];
#pragma unroll
    for (int mt = 0; mt < 4; ++mt)
#pragma unroll
        for (int q = 0; q < 4; ++q) {
            const int n2 = 16 * mt + 4 * u + q;
            cinit[mt][q]    = b2[n2];
            w3c[mt * 4 + q] = W3[n2];
        }
    const float b3v = b3[0];

#pragma unroll
    for (int p = 0; p < 4; ++p) { KEEPV(A1[p][0]); KEEPV(A1[p][1]); }
#pragma unroll
    for (int mt = 0; mt < 4; ++mt)
#pragma unroll
        for (int p = 0; p < 4; ++p) KEEPV(A2[mt][p]);
#pragma unroll
    for (int mt = 0; mt < 4; ++mt) KEEPV(cinit[mt]);
#pragma unroll
    for (int q = 0; q < 16; ++q) KEEPF(w3c[q]);

    const int gw = blockIdx.x * 4 + wid;
    float psum = 0.f;                    // probe accumulator

    for (int pt = gw; pt < UNITS; pt += NWAVE) {
        const int b   = pt >> 15;        // 1024*32 units per batch
        const int rem = pt & 32767;
        const int i   = rem >> 5;        // vertex i (0..1023)
        const int j0  = (rem & 31) << 5; // j block base (0..992)
        if (j0 + 31 <= i) continue;      // entire unit at/below diagonal

        // ---- features: vi broadcast + coalesced vj, or synthetic ----
        bf16x8 bfv[2];
        if constexpr (PROBE == 0) {
            const float* pvi = vertices + (b * VV + i) * 3;
            const float vi0 = pvi[0], vi1 = pvi[1], vi2 = pvi[2];
#pragma unroll
            for (int s = 0; s < 2; ++s) {
                const int j = j0 + s * 16 + col;          // <= 1023 always
                const float* pvj = vertices + (b * VV + j) * 3;
                u32x4 fb;
                fb[0] = pkbf(vi0, vi1);
                fb[1] = pkbf(vi2, pvj[0]);
                fb[2] = pkbf(pvj[1], pvj[2]);
                fb[3] = 0x00003F80u;      // bf16(1.0) in k=6 (bias), 0 in k=7
                bfv[s] = __builtin_bit_cast(bf16x8, fb);
            }
        } else {
#pragma unroll
            for (int s = 0; s < 2; ++s) {
                u32x4 fb;
                fb[0] = pkbf((float)(pt & 7), 0.5f);      // pt-dep, unhoistable
                fb[1] = pkbf((float)col * 0.125f, 0.25f);
                fb[2] = pkbf((float)(s + 1), -0.5f);
                fb[3] = 0x00003F80u;
                bfv[s] = __builtin_bit_cast(bf16x8, fb);
            }
        }

        // ---- fused L1 -> relu/pack -> L2 (R6-identical) ----
        f32x4 d2[2][4];
#pragma unroll
        for (int s = 0; s < 2; ++s) {
            f32x4 dA = __builtin_amdgcn_mfma_f32_16x16x32_bf16(A1[0][0], bfv[s], zero4, 0, 0, 0);
            f32x4 dB = __builtin_amdgcn_mfma_f32_16x16x32_bf16(A1[0][1], bfv[s], zero4, 0, 0, 0);
            bf16x8 Bh = relu_pack(dA, dB);
            d2[s][0] = __builtin_amdgcn_mfma_f32_16x16x32_bf16(A2[0][0], Bh, cinit[0], 0, 0, 0);
            d2[s][1] = __builtin_amdgcn_mfma_f32_16x16x32_bf16(A2[1][0], Bh, cinit[1], 0, 0, 0);
            d2[s][2] = __builtin_amdgcn_mfma_f32_16x16x32_bf16(A2[2][0], Bh, cinit[2], 0, 0, 0);
            d2[s][3] = __builtin_amdgcn_mfma_f32_16x16x32_bf16(A2[3][0], Bh, cinit[3], 0, 0, 0);
        }
#pragma unroll
        for (int p = 1; p < 4; ++p) {
#pragma unroll
            for (int s = 0; s < 2; ++s) {
                f32x4 dA = __builtin_amdgcn_mfma_f32_16x16x32_bf16(A1[p][0], bfv[s], zero4, 0, 0, 0);
                f32x4 dB = __builtin_amdgcn_mfma_f32_16x16x32_bf16(A1[p][1], bfv[s], zero4, 0, 0, 0);
                bf16x8 Bh = relu_pack(dA, dB);
                d2[s][0] = __builtin_amdgcn_mfma_f32_16x16x32_bf16(A2[0][p], Bh, d2[s][0], 0, 0, 0);
                d2[s][1] = __builtin_amdgcn_mfma_f32_16x16x32_bf16(A2[1][p], Bh, d2[s][1], 0, 0, 0);
                d2[s][2] = __builtin_amdgcn_mfma_f32_16x16x32_bf16(A2[2][p], Bh, d2[s][2], 0, 0, 0);
                d2[s][3] = __builtin_amdgcn_mfma_f32_16x16x32_bf16(A2[3][p], Bh, d2[s][3], 0, 0, 0);
            }
        }

        // ---- layer 3 + sigmoid; store (real) or accumulate (probe) ----
#pragma unroll
        for (int s = 0; s < 2; ++s) {
            float a0 = 0.f, a1 = 0.f, a2 = 0.f, a3 = 0.f;
#pragma unroll
            for (int q = 0; q < 4; ++q) {
                a0 = fmaf(fmaxf(d2[s][0][q], 0.f), w3c[q],      a0);
                a1 = fmaf(fmaxf(d2[s][1][q], 0.f), w3c[4 + q],  a1);
                a2 = fmaf(fmaxf(d2[s][2][q], 0.f), w3c[8 + q],  a2);
                a3 = fmaf(fmaxf(d2[s][3][q], 0.f), w3c[12 + q], a3);
            }
            float acc = (a0 + a1) + (a2 + a3);
            acc += __shfl_xor(acc, 16);
            acc += __shfl_xor(acc, 32);

            if constexpr (PROBE == 0) {
                const int j = j0 + s * 16 + col;
                if (u == 0 && j > i) {
                    const float x = acc + b3v;
                    const float prob = __builtin_amdgcn_rcpf(1.0f + __expf(-x));
                    const int e = (i * (2 * VV - 1 - i)) / 2 + (j - i - 1);
                    out[b * EE + e] = prob;                    // contiguous run
                    if (b == 0)
                        *(float2*)(&out[BE + 2 * e]) =
                            make_float2((float)i, (float)j);
                }
            } else {
                const float x = acc + b3v;
                psum += __builtin_amdgcn_rcpf(1.0f + __expf(-x));
            }
        }
    }

    if constexpr (PROBE == 1) {
        asm volatile("" :: "v"(psum));   // keep entire chain live (rule 17)
    }
}

extern "C" void kernel_launch(void* const* d_in, const int* in_sizes, int n_in,
                              void* d_out, int out_size, void* d_ws, size_t ws_size,
                              hipStream_t stream) {
    const float* vertices = (const float*)d_in[0];
    const float* W1 = (const float*)d_in[1];
    const float* b1 = (const float*)d_in[2];
    const float* W2 = (const float*)d_in[3];
    const float* b2 = (const float*)d_in[4];
    const float* W3 = (const float*)d_in[5];
    const float* b3 = (const float*)d_in[6];
    float* out = (float*)d_out;

    // probe first (no stores), real kernel last (writes the actual output)
    edge_blk<1><<<NBLK, NTHR, 0, stream>>>(vertices, W1, b1, W2, b2, W3, b3, out);
    edge_blk<0><<<NBLK, NTHR, 0, stream>>>(vertices, W1, b1, W2, b2, W3, b3, out);
}